// Round 1
// baseline (1695.792 us; speedup 1.0000x reference)
//
#include <hip/hip_runtime.h>
#include <hip/hip_bf16.h>

#define N_NODES 100000
#define N_EDGES 600000
#define DIM     128
#define N_REL   8
#define N_GRAPH 64
#define N_LAYER 3
#define NR      (N_NODES * N_REL)   // 800000
#define NB1     782                 // ceil(NR / 1024)

typedef __attribute__((ext_vector_type(8))) short short8;
typedef __attribute__((ext_vector_type(4))) float float4v;

__device__ __forceinline__ float bflo(unsigned int u) {
    return __builtin_bit_cast(float, u << 16);
}
__device__ __forceinline__ float bfhi(unsigned int u) {
    return __builtin_bit_cast(float, u & 0xffff0000u);
}
__device__ __forceinline__ unsigned short f2bf(float f) {
    unsigned int u = __builtin_bit_cast(unsigned int, f);
    u += 0x7fffu + ((u >> 16) & 1u);          // RNE
    return (unsigned short)(u >> 16);
}
__device__ __forceinline__ unsigned int pack2(float a, float b) {
    return (unsigned int)f2bf(a) | ((unsigned int)f2bf(b) << 16);
}

// ---------------- utility: zero int buffer ----------------
__global__ void k_zero(int* __restrict__ p, int n) {
    int i = blockIdx.x * 256 + threadIdx.x;
    if (i < n) p[i] = 0;
}

// ---------------- counting sort of edges by seg = dst*R + type ----------------
__global__ void k_hist(const int* __restrict__ ei, const int* __restrict__ et,
                       int* __restrict__ counts) {
    int e = blockIdx.x * 256 + threadIdx.x;
    if (e < N_EDGES) {
        int seg = ei[N_EDGES + e] * N_REL + et[e];
        atomicAdd(&counts[seg], 1);
    }
}

__global__ __launch_bounds__(256) void k_scan1(const int* __restrict__ c,
                                               int* __restrict__ part,
                                               int* __restrict__ bsum) {
    __shared__ int sh[256];
    int t = threadIdx.x;
    int base = blockIdx.x * 1024 + t * 4;
    int v0 = (base + 0 < NR) ? c[base + 0] : 0;
    int v1 = (base + 1 < NR) ? c[base + 1] : 0;
    int v2 = (base + 2 < NR) ? c[base + 2] : 0;
    int v3 = (base + 3 < NR) ? c[base + 3] : 0;
    int tot = v0 + v1 + v2 + v3;
    sh[t] = tot;
    __syncthreads();
    for (int off = 1; off < 256; off <<= 1) {
        int x = (t >= off) ? sh[t - off] : 0;
        __syncthreads();
        sh[t] += x;
        __syncthreads();
    }
    int exc = sh[t] - tot;
    if (base + 0 < NR) part[base + 0] = exc;
    if (base + 1 < NR) part[base + 1] = exc + v0;
    if (base + 2 < NR) part[base + 2] = exc + v0 + v1;
    if (base + 3 < NR) part[base + 3] = exc + v0 + v1 + v2;
    if (t == 255) bsum[blockIdx.x] = sh[t];
}

__global__ __launch_bounds__(1024) void k_scan2(int* __restrict__ bsum, int nb) {
    __shared__ int sh[1024];
    int t = threadIdx.x;
    int v = (t < nb) ? bsum[t] : 0;
    sh[t] = v;
    __syncthreads();
    for (int off = 1; off < 1024; off <<= 1) {
        int x = (t >= off) ? sh[t - off] : 0;
        __syncthreads();
        sh[t] += x;
        __syncthreads();
    }
    if (t < nb) bsum[t] = sh[t] - v;   // exclusive block offsets
}

__global__ void k_scan3(const int* __restrict__ part, const int* __restrict__ bsum,
                        int* __restrict__ rowptr, int* __restrict__ cursor) {
    int i = blockIdx.x * 256 + threadIdx.x;
    if (i < NR) {
        int v = part[i] + bsum[i >> 10];
        rowptr[i] = v;
        cursor[i] = v;
    }
    if (i == 0) rowptr[NR] = N_EDGES;
}

__global__ void k_scatter(const int* __restrict__ ei, const int* __restrict__ et,
                          int* __restrict__ cursor, int* __restrict__ srcs) {
    int e = blockIdx.x * 256 + threadIdx.x;
    if (e < N_EDGES) {
        int seg = ei[N_EDGES + e] * N_REL + et[e];
        int p = atomicAdd(&cursor[seg], 1);
        srcs[p] = ei[e];
    }
}

// ---------------- x0 = node_emb[node_type], stored bf16x2 ----------------
__global__ void k_gather(const int* __restrict__ nt, const float* __restrict__ emb,
                         unsigned int* __restrict__ x2) {
    int gid = blockIdx.x * 256 + threadIdx.x;
    if (gid < N_NODES * 64) {
        int n = gid >> 6, c2 = gid & 63;
        const float* row = emb + (size_t)nt[n] * DIM + c2 * 2;
        x2[gid] = pack2(row[0], row[1]);
    }
}

// ---------------- weight prep: WT[l][chunk][n][k] bf16 (transposed, MFMA-B-friendly) ----
__global__ void k_wprep(const float* __restrict__ relw, const float* __restrict__ rootw,
                        unsigned short* __restrict__ WT) {
    int gid = blockIdx.x * 256 + threadIdx.x;
    if (gid < N_LAYER * 9 * 16384) {
        int l = gid / (9 * 16384);
        int rem = gid - l * 9 * 16384;
        int c = rem >> 14;
        int idx = rem & 16383;
        int n = idx >> 7, k = idx & 127;
        float w = (c < 8) ? relw[(((size_t)l * 8 + c) * 128 + k) * 128 + n]
                          : rootw[((size_t)l * 128 + k) * 128 + n];
        WT[gid] = f2bf(w);
    }
}

// ---------------- fused RGCN layer: aggregate-into-LDS + MFMA GEMM ----------------
// out[n,:] = relu( sum_r mean_r[n,:] @ Wrel[r] + x[n,:] @ Wroot + bias )
#define BM 64
__global__ __launch_bounds__(256) void k_layer(
    const unsigned int* __restrict__ xin,   // [N][64] bf16x2
    unsigned int* __restrict__ xout,        // [N][64] bf16x2
    const int* __restrict__ rowptr,         // [NR+1]
    const int* __restrict__ srcs,           // [E] sorted by seg
    const unsigned short* __restrict__ WT,  // [9][128(n)][128(k)] bf16
    const float* __restrict__ bias)         // [128]
{
    __shared__ __align__(16) unsigned int Als[BM * 68];    // 64 rows, stride 136 bf16
    __shared__ __align__(16) unsigned int Bls[128 * 68];   // 128 rows, stride 136 bf16
    const int t = threadIdx.x;
    const int wv = t >> 6, lane = t & 63;
    const int quad = lane >> 4, l15 = lane & 15;
    const int m0 = blockIdx.x * BM;
    const int col2 = t & 63;     // uint (2-col) index within a row
    const int rq = t >> 6;       // row group

    float4v acc[8];
#pragma unroll
    for (int nt = 0; nt < 8; ++nt) {
        float bc = bias[nt * 16 + l15];
        acc[nt] = (float4v){bc, bc, bc, bc};
    }

    for (int c = 0; c < 9; ++c) {
        // ---- build A tile (bf16) ----
        if (c < 8) {
            for (int i = 0; i < 16; ++i) {
                int ml = rq + 4 * i;
                int m = m0 + ml;
                float a0 = 0.f, a1 = 0.f, inv = 0.f;
                if (m < N_NODES) {
                    int seg = m * N_REL + c;
                    int s = rowptr[seg], e = rowptr[seg + 1];
                    if (e > s) inv = 1.0f / (float)(e - s);
                    for (int j = s; j < e; ++j) {
                        unsigned int u = xin[(size_t)srcs[j] * 64 + col2];
                        a0 += bflo(u);
                        a1 += bfhi(u);
                    }
                }
                Als[ml * 68 + col2] = pack2(a0 * inv, a1 * inv);
            }
        } else {
            for (int i = 0; i < 16; ++i) {
                int ml = rq + 4 * i;
                int m = m0 + ml;
                Als[ml * 68 + col2] = (m < N_NODES) ? xin[(size_t)m * 64 + col2] : 0u;
            }
        }
        // ---- load B tile (already transposed [n][k]) ----
        {
            const unsigned int* Wc = (const unsigned int*)(WT + c * 16384);
#pragma unroll
            for (int i = 0; i < 32; ++i) {
                int idx = t + 256 * i;          // 0..8191 uints
                int n = idx >> 6, ku = idx & 63;
                Bls[n * 68 + ku] = Wc[idx];
            }
        }
        __syncthreads();
        // ---- MFMA: 4 K-steps x 8 N-tiles ----
        const short* As = (const short*)Als;
        const short* Bs = (const short*)Bls;
#pragma unroll
        for (int kk = 0; kk < 4; ++kk) {
            short8 a = *(const short8*)(As + (wv * 16 + l15) * 136 + kk * 32 + quad * 8);
#pragma unroll
            for (int nt = 0; nt < 8; ++nt) {
                short8 b = *(const short8*)(Bs + (nt * 16 + l15) * 136 + kk * 32 + quad * 8);
                acc[nt] = __builtin_amdgcn_mfma_f32_16x16x32_bf16(a, b, acc[nt], 0, 0, 0);
            }
        }
        __syncthreads();
    }
    // ---- epilogue: relu, store bf16 ----
    unsigned short* outs = (unsigned short*)xout;
#pragma unroll
    for (int nt = 0; nt < 8; ++nt) {
        int colg = nt * 16 + l15;
#pragma unroll
        for (int i = 0; i < 4; ++i) {
            int row = m0 + wv * 16 + quad * 4 + i;
            if (row < N_NODES) {
                float v = acc[nt][i];
                v = v > 0.f ? v : 0.f;
                outs[(size_t)row * 128 + colg] = f2bf(v);
            }
        }
    }
}

// ---------------- global mean pool (batch is sorted) ----------------
__global__ __launch_bounds__(256) void k_pool(const unsigned int* __restrict__ x2,
                                              const int* __restrict__ batch,
                                              float* __restrict__ gsum,
                                              int* __restrict__ gcnt) {
    int wv = threadIdx.x >> 6, lane = threadIdx.x & 63;
    int cid = blockIdx.x * 4 + wv;
    int n0 = cid * 512;
    if (n0 >= N_NODES) return;
    int n1 = n0 + 512;
    if (n1 > N_NODES) n1 = N_NODES;
    float a0 = 0.f, a1 = 0.f;
    int run = 0;
    int cur = batch[n0];
    for (int n = n0; n < n1; ++n) {
        int b = batch[n];
        if (b != cur) {
            atomicAdd(&gsum[cur * 128 + lane * 2], a0);
            atomicAdd(&gsum[cur * 128 + lane * 2 + 1], a1);
            if (lane == 0) atomicAdd(&gcnt[cur], run);
            a0 = a1 = 0.f;
            run = 0;
            cur = b;
        }
        unsigned int u = x2[(size_t)n * 64 + lane];
        a0 += bflo(u);
        a1 += bfhi(u);
        ++run;
    }
    atomicAdd(&gsum[cur * 128 + lane * 2], a0);
    atomicAdd(&gsum[cur * 128 + lane * 2 + 1], a1);
    if (lane == 0) atomicAdd(&gcnt[cur], run);
}

// ---------------- MLP heads (fp32) ----------------
__global__ __launch_bounds__(128) void k_heads(
    const float* __restrict__ gsum, const int* __restrict__ gcnt,
    const float* __restrict__ rw1, const float* __restrict__ rb1,
    const float* __restrict__ rw2, const float* __restrict__ rb2,
    const float* __restrict__ sw1, const float* __restrict__ sb1,
    const float* __restrict__ sw2, const float* __restrict__ sb2,
    float* __restrict__ out) {
    __shared__ float g[128];
    __shared__ float parts[2];
    int b = blockIdx.x, t = threadIdx.x;
    int c = gcnt[b];
    float invc = 1.0f / (float)(c > 0 ? c : 1);
    g[t] = gsum[b * 128 + t] * invc;
    __syncthreads();
    // risk head
    float acc = rb1[t];
    for (int d = 0; d < 128; ++d) acc += g[d] * rw1[d * 128 + t];
    float h = acc > 0.f ? acc : 0.f;
    float p = h * rw2[t];
    for (int o = 32; o > 0; o >>= 1) p += __shfl_down(p, o);
    if ((t & 63) == 0) parts[t >> 6] = p;
    __syncthreads();
    if (t == 0) out[b] = parts[0] + parts[1] + rb2[0];
    __syncthreads();
    // safe head
    acc = sb1[t];
    for (int d = 0; d < 128; ++d) acc += g[d] * sw1[d * 128 + t];
    h = acc > 0.f ? acc : 0.f;
    p = h * sw2[t];
    for (int o = 32; o > 0; o >>= 1) p += __shfl_down(p, o);
    if ((t & 63) == 0) parts[t >> 6] = p;
    __syncthreads();
    if (t == 0) out[64 + b] = parts[0] + parts[1] + sb2[0];
}

extern "C" void kernel_launch(void* const* d_in, const int* in_sizes, int n_in,
                              void* d_out, int out_size, void* d_ws, size_t ws_size,
                              hipStream_t stream) {
    const int*   node_type  = (const int*)d_in[0];
    const int*   edge_index = (const int*)d_in[1];
    const int*   edge_type  = (const int*)d_in[2];
    const int*   batch      = (const int*)d_in[3];
    const float* node_emb   = (const float*)d_in[4];
    const float* rel_w      = (const float*)d_in[5];
    const float* root_w     = (const float*)d_in[6];
    const float* bias       = (const float*)d_in[7];
    const float* rw1        = (const float*)d_in[8];
    const float* rb1        = (const float*)d_in[9];
    const float* rw2        = (const float*)d_in[10];
    const float* rb2        = (const float*)d_in[11];
    const float* sw1        = (const float*)d_in[12];
    const float* sb1        = (const float*)d_in[13];
    const float* sw2        = (const float*)d_in[14];
    const float* sb2        = (const float*)d_in[15];
    float* out = (float*)d_out;

    char* ws = (char*)d_ws;
    size_t off = 0;
    auto alloc = [&](size_t bytes) -> void* {
        void* p = ws + off;
        off += (bytes + 255) & ~(size_t)255;
        return p;
    };
    unsigned int*   xa     = (unsigned int*)alloc((size_t)N_NODES * 64 * 4);
    unsigned int*   xb     = (unsigned int*)alloc((size_t)N_NODES * 64 * 4);
    int*            rowptr = (int*)alloc((size_t)(NR + 1) * 4);
    int*            cursor = (int*)alloc((size_t)NR * 4);   // also scan "part" temp
    int*            counts = (int*)alloc((size_t)NR * 4);
    int*            srcs   = (int*)alloc((size_t)N_EDGES * 4);
    int*            bsum   = (int*)alloc(1024 * 4);
    unsigned short* WT     = (unsigned short*)alloc((size_t)N_LAYER * 9 * 16384 * 2);
    float*          gsum   = (float*)alloc((64 * 128 + 64) * 4);
    int*            gcnt   = (int*)(gsum + 64 * 128);
    if (off > ws_size) return;   // workspace insufficient — fail visibly

    // edge sort (counting sort by dst*R + type)
    k_zero<<<(NR + 255) / 256, 256, 0, stream>>>(counts, NR);
    k_zero<<<(64 * 128 + 64 + 255) / 256, 256, 0, stream>>>((int*)gsum, 64 * 128 + 64);
    k_hist<<<(N_EDGES + 255) / 256, 256, 0, stream>>>(edge_index, edge_type, counts);
    k_scan1<<<NB1, 256, 0, stream>>>(counts, cursor, bsum);
    k_scan2<<<1, 1024, 0, stream>>>(bsum, NB1);
    k_scan3<<<(NR + 255) / 256, 256, 0, stream>>>(cursor, bsum, rowptr, cursor);
    k_scatter<<<(N_EDGES + 255) / 256, 256, 0, stream>>>(edge_index, edge_type, cursor, srcs);

    // x0 gather + weight prep
    k_gather<<<(N_NODES * 64 + 255) / 256, 256, 0, stream>>>(node_type, node_emb, xa);
    k_wprep<<<(N_LAYER * 9 * 16384 + 255) / 256, 256, 0, stream>>>(rel_w, root_w, WT);

    // 3 fused RGCN layers
    const int mblocks = (N_NODES + BM - 1) / BM;
    k_layer<<<mblocks, 256, 0, stream>>>(xa, xb, rowptr, srcs, WT + 0 * 9 * 16384, bias + 0 * 128);
    k_layer<<<mblocks, 256, 0, stream>>>(xb, xa, rowptr, srcs, WT + 1 * 9 * 16384, bias + 1 * 128);
    k_layer<<<mblocks, 256, 0, stream>>>(xa, xb, rowptr, srcs, WT + 2 * 9 * 16384, bias + 2 * 128);

    // pool + heads
    k_pool<<<(N_NODES + 2047) / 2048, 256, 0, stream>>>(xb, batch, gsum, gcnt);
    k_heads<<<64, 128, 0, stream>>>(gsum, gcnt, rw1, rb1, rw2, rb2,
                                    sw1, sb1, sw2, sb2, out);
}